// Round 8
// baseline (328.586 us; speedup 1.0000x reference)
//
#include <hip/hip_runtime.h>
#include <math.h>

#define NL 45
#define START_IDX 43
#define STOP_IDX 44

#define FOR12(F) F(0) F(1) F(2) F(3) F(4) F(5) F(6) F(7) F(8) F(9) F(10) F(11)

__device__ __forceinline__ float wave_max64(float v) {
    v = fmaxf(v, __shfl_xor(v, 32, 64));
    v = fmaxf(v, __shfl_xor(v, 16, 64));
    v = fmaxf(v, __shfl_xor(v, 8, 64));
    v = fmaxf(v, __shfl_xor(v, 4, 64));
    v = fmaxf(v, __shfl_xor(v, 2, 64));
    v = fmaxf(v, __shfl_xor(v, 1, 64));
    return v;
}

__device__ __forceinline__ float wave_sum64(float v) {
    v += __shfl_xor(v, 32, 64);
    v += __shfl_xor(v, 16, 64);
    v += __shfl_xor(v, 8, 64);
    v += __shfl_xor(v, 4, 64);
    v += __shfl_xor(v, 2, 64);
    v += __shfl_xor(v, 1, 64);
    return v;
}

// 4 waves per block, one batch per block; lane i (<45) owns label i in EVERY
// wave (q replicated across waves). Wave w owns reduction columns
// j in [12w, 12w+12): per step it does 12 readlanes + 12 fmas, writes its 45
// partials to LDS, one barrier, then all waves rebuild q identically from 4
// ds_reads. Parity double-buffer makes 1 barrier/step race-free.
// Why: r7 measured 586 cyc/step at 1 wave/SIMD with ~420 cyc of bare latency
// (6 serial bpermutes in renorm, readlane chains) that nothing could hide.
// This gives 4 waves/SIMD from independent blocks (TLP hides latency) and
// quarters the serial readlane batch. Renorm is shuffle-free: bitwise-max of
// SGPR-resident qb's (exponent monotone in bits for positive floats),
// consensus via the existing LDS round, exact power-of-2 ledger.
__global__ __launch_bounds__(256, 4)
void crf_fwd_kernel(
        const float* __restrict__ logits,
        const int* __restrict__ lens,
        const float* __restrict__ trans,
        float* __restrict__ out,
        int S) {
    const int b = blockIdx.x;
    const int tid = (int)threadIdx.x;
    const int lane = tid & 63;
    const int w = tid >> 6;                 // wave 0..3
    const bool real = lane < NL;
    const int rl = real ? lane : 0;         // clamped label index (addresses)

    __shared__ float parts[2][4][64];       // [parity][wave][label-lane]
    __shared__ __align__(16) int exps[2][4];

    // --- E subset for this wave: e_J = exp(trans[rl][12w+J]), 0 if j>=45/pad ---
#define E_DECL(J) const int j##J = 12 * w + (J); \
    const float e##J = (real && j##J < NL) \
        ? __expf(trans[rl * NL + ((j##J) < NL ? (j##J) : 0)]) : 0.0f;
    FOR12(E_DECL)
#undef E_DECL

    const float tstop = trans[STOP_IDX * NL + rl];
    const int len = lens[b];                // uniform per block

    // --- init: alpha0 = -1e4 (exp underflows to exactly 0), 0 at START ---
    float q = (real && lane == START_IDX) ? 1.0f : 0.0f;
    int esum = 0;                           // alpha = log(q) + esum*ln2 (exact)
    int pa = 0;                             // LDS parity

    const float* lp = logits + (size_t)b * (size_t)S * NL + rl;
    const int tmax = S - 1;
#define LD(T) lp[(size_t)(((T) < tmax) ? (T) : tmax) * NL]
    float f0 = LD(0), f1 = LD(1), f2 = LD(2), f3 = LD(3);
    float p0 = LD(4), p1 = LD(5), p2 = LD(6), p3 = LD(7);

#define RDL(J) const float qb##J = __uint_as_float( \
        __builtin_amdgcn_readlane(__float_as_uint(q), j##J));
#define MACJ(J) acc[(J) & 3] = fmaf(e##J, qb##J, acc[(J) & 3]);
#define MAXQ(J) { const unsigned u = __float_as_uint(qb##J); mx = (u > mx) ? u : mx; }

    // One step. RN=1 (chunk-last): piggyback exponent consensus on the barrier.
#define STEP(K, RN) { \
        const float el = __expf(f##K); \
        FOR12(RDL) \
        __builtin_amdgcn_sched_barrier(0); \
        float acc[4] = {0.0f, 0.0f, 0.0f, 0.0f}; \
        FOR12(MACJ) \
        parts[pa][w][lane] = (acc[0] + acc[1]) + (acc[2] + acc[3]); \
        if (RN) { \
            unsigned mx = __float_as_uint(qb0); \
            MAXQ(1) MAXQ(2) MAXQ(3) MAXQ(4) MAXQ(5) MAXQ(6) MAXQ(7) \
            MAXQ(8) MAXQ(9) MAXQ(10) MAXQ(11) \
            if (lane == 0) exps[pa][w] = (int)mx; \
        } \
        __syncthreads(); \
        const float Ssum = (parts[pa][0][lane] + parts[pa][1][lane]) \
                         + (parts[pa][2][lane] + parts[pa][3][lane]); \
        const float qn = el * Ssum; \
        q = (t0 + (K) < len) ? qn : q; \
        if (RN) { \
            const int4 ev = *((const int4*)exps[pa]); \
            int m01 = (ev.x > ev.y) ? ev.x : ev.y; \
            int m23 = (ev.z > ev.w) ? ev.z : ev.w; \
            const int mex = (m01 > m23) ? m01 : m23; \
            const int ex = (mex >> 23) - 127; \
            q = ldexpf(q, -ex); \
            esum += ex; \
        } \
        pa ^= 1; \
    }

#pragma unroll 2
    for (int t0 = 0; t0 < len; t0 += 4) {
        // issue loads for chunk t0+8..t0+11 (2 chunks ahead, clamped)
        const float n0 = LD(t0 + 8), n1 = LD(t0 + 9);
        const float n2 = LD(t0 + 10), n3 = LD(t0 + 11);

        STEP(0, 0) STEP(1, 0) STEP(2, 0) STEP(3, 1)

        f0 = p0; f1 = p1; f2 = p2; f3 = p3;
        p0 = n0; p1 = n1; p2 = n2; p3 = n3;
    }
#undef STEP
#undef MAXQ
#undef MACJ
#undef RDL
#undef LD

    // --- epilogue (wave 0 only; q and esum identical in all waves) ---
    if (w == 0) {
        const float a = __logf(q) + tstop;   // q=0 (pads) -> -inf
        const float mm = wave_max64(a);
        const float e = __expf(a - mm);      // exp(-inf - mm) = 0
        const float ssum = wave_sum64(e);
        if (lane == 0) {
            const float M = (float)esum * 0.69314718055994531f;
            out[b] = M + mm + __logf(ssum);
        }
    }
}

extern "C" void kernel_launch(void* const* d_in, const int* in_sizes, int n_in,
                              void* d_out, int out_size, void* d_ws, size_t ws_size,
                              hipStream_t stream) {
    const float* logits = (const float*)d_in[0];
    const int* lens = (const int*)d_in[1];
    const float* trans = (const float*)d_in[2];
    float* out = (float*)d_out;

    const int B = in_sizes[1];                       // 1024
    const int S = in_sizes[0] / (B * NL);            // 512

    crf_fwd_kernel<<<B, 256, 0, stream>>>(logits, lens, trans, out, S);
}

// Round 9
// 261.970 us; speedup vs baseline: 1.2543x; 1.2543x over previous
//
#include <hip/hip_runtime.h>
#include <math.h>

#define NL 45
#define START_IDX 43
#define STOP_IDX 44

__device__ __forceinline__ float wave_max64(float v) {
    v = fmaxf(v, __shfl_xor(v, 32, 64));
    v = fmaxf(v, __shfl_xor(v, 16, 64));
    v = fmaxf(v, __shfl_xor(v, 8, 64));
    v = fmaxf(v, __shfl_xor(v, 4, 64));
    v = fmaxf(v, __shfl_xor(v, 2, 64));
    v = fmaxf(v, __shfl_xor(v, 1, 64));
    return v;
}

__device__ __forceinline__ float wave_sum64(float v) {
    v += __shfl_xor(v, 32, 64);
    v += __shfl_xor(v, 16, 64);
    v += __shfl_xor(v, 8, 64);
    v += __shfl_xor(v, 4, 64);
    v += __shfl_xor(v, 2, 64);
    v += __shfl_xor(v, 1, 64);
    return v;
}

// One wave per batch element; lane i (<45) owns label i. Exp-domain CRF:
//   q'_i = exp(logit[t][i]) * sum_j exp(trans[i][j]) * q_j
// r8 lesson: wall time = len * single-chain LATENCY; multi-wave LDS round
// trips per step (226us) lose to the in-wave readlane chain (125us).
// This version shortens the r7 chain:
//  (a) renorm via SALU: qb's are SGPR-resident; uint-max tree on the scalar
//      pipe (parallel with VALU), ex=(bits>>23)-127, one v_ldexp on chain.
//      Replaces 6 serial ds_bpermutes + frexp/ldexp every 4 steps.
//  (b) rdl/fma interleaved at distance 12 (no monolithic sched_barrier):
//      fma issue overlaps rdl issue; hazard distance >= 12 kept.
//  (c) 8 accumulators, first 8 initialized by mul: fma depth 12 -> 6.
__global__ __attribute__((amdgpu_flat_work_group_size(64, 64),
                          amdgpu_waves_per_eu(1, 1)))
void crf_fwd_kernel(
        const float* __restrict__ logits,
        const int* __restrict__ lens,
        const float* __restrict__ trans,
        float* __restrict__ out,
        int S) {
    const int b = blockIdx.x;
    const int lane = threadIdx.x;
    const bool real = lane < NL;
    const int rl = real ? lane : 0;   // clamped label index for safe addresses

#define FOR45(F) \
  F(0) F(1) F(2) F(3) F(4) F(5) F(6) F(7) F(8) F(9) \
  F(10) F(11) F(12) F(13) F(14) F(15) F(16) F(17) F(18) F(19) \
  F(20) F(21) F(22) F(23) F(24) F(25) F(26) F(27) F(28) F(29) \
  F(30) F(31) F(32) F(33) F(34) F(35) F(36) F(37) F(38) F(39) \
  F(40) F(41) F(42) F(43) F(44)

    // --- one-time: E row as 45 named scalars, pinned in VGPRs ---
#define E_DECL(J) float e##J = real ? __expf(trans[rl * NL + (J)]) : 0.0f;
    FOR45(E_DECL)
#undef E_DECL
    asm volatile("" : "+v"(e0), "+v"(e1), "+v"(e2), "+v"(e3), "+v"(e4),
                      "+v"(e5), "+v"(e6), "+v"(e7), "+v"(e8), "+v"(e9),
                      "+v"(e10), "+v"(e11), "+v"(e12), "+v"(e13), "+v"(e14),
                      "+v"(e15), "+v"(e16), "+v"(e17), "+v"(e18), "+v"(e19),
                      "+v"(e20), "+v"(e21), "+v"(e22));
    asm volatile("" : "+v"(e23), "+v"(e24), "+v"(e25), "+v"(e26), "+v"(e27),
                      "+v"(e28), "+v"(e29), "+v"(e30), "+v"(e31), "+v"(e32),
                      "+v"(e33), "+v"(e34), "+v"(e35), "+v"(e36), "+v"(e37),
                      "+v"(e38), "+v"(e39), "+v"(e40), "+v"(e41), "+v"(e42),
                      "+v"(e43), "+v"(e44));

    const float tstop = trans[STOP_IDX * NL + rl];
    const int len = lens[b];

    // --- init: alpha0 = -1e4 (exp underflows to exactly 0), 0 at START ---
    float q = (real && lane == START_IDX) ? 1.0f : 0.0f;
    int esum = 0;   // alpha = log(q) + esum * ln2  (exact power-of-2 ledger)

    const float* lp = logits + (size_t)b * (size_t)S * NL + rl;
    const int tmax = S - 1;

#define LD(T) lp[(size_t)(((T) < tmax) ? (T) : tmax) * NL]
    float f0 = LD(0), f1 = LD(1), f2 = LD(2), f3 = LD(3);
    float p0 = LD(4), p1 = LD(5), p2 = LD(6), p3 = LD(7);

#define RDL(J) const float qb##J = __uint_as_float( \
        __builtin_amdgcn_readlane(__float_as_uint(q), (J)));
#define INI(J) acc[(J) & 7] = e##J * qb##J;                 // J = 0..7
#define MAC(J) acc[(J) & 7] = fmaf(e##J, qb##J, acc[(J) & 7]);
#define MXQ(J) { const unsigned u##J = __float_as_uint(qb##J); \
                 mx = (u##J > mx) ? u##J : mx; }

    // One step. Source order: 12 rdl, then (rdl, mac) pairs at distance 12,
    // tail macs. RN=1: SALU max over the 45 SGPR qb's -> exact pow2 renorm.
#define STEP(K, RN) { \
        const float el = __expf(f##K); \
        float acc[8]; \
        RDL(0) RDL(1) RDL(2) RDL(3) RDL(4) RDL(5) \
        RDL(6) RDL(7) RDL(8) RDL(9) RDL(10) RDL(11) \
        RDL(12) INI(0)  RDL(13) INI(1)  RDL(14) INI(2)  RDL(15) INI(3) \
        RDL(16) INI(4)  RDL(17) INI(5)  RDL(18) INI(6)  RDL(19) INI(7) \
        RDL(20) MAC(8)  RDL(21) MAC(9)  RDL(22) MAC(10) RDL(23) MAC(11) \
        RDL(24) MAC(12) RDL(25) MAC(13) RDL(26) MAC(14) RDL(27) MAC(15) \
        RDL(28) MAC(16) RDL(29) MAC(17) RDL(30) MAC(18) RDL(31) MAC(19) \
        RDL(32) MAC(20) RDL(33) MAC(21) RDL(34) MAC(22) RDL(35) MAC(23) \
        RDL(36) MAC(24) RDL(37) MAC(25) RDL(38) MAC(26) RDL(39) MAC(27) \
        RDL(40) MAC(28) RDL(41) MAC(29) RDL(42) MAC(30) RDL(43) MAC(31) \
        RDL(44) MAC(32) \
        MAC(33) MAC(34) MAC(35) MAC(36) MAC(37) MAC(38) \
        MAC(39) MAC(40) MAC(41) MAC(42) MAC(43) MAC(44) \
        const float s01 = acc[0] + acc[1], s23 = acc[2] + acc[3]; \
        const float s45 = acc[4] + acc[5], s67 = acc[6] + acc[7]; \
        const float qn = el * ((s01 + s23) + (s45 + s67)); \
        q = (t0 + (K) < len) ? qn : q; \
        if (RN) { \
            unsigned mx = __float_as_uint(qb0); \
            MXQ(1) MXQ(2) MXQ(3) MXQ(4) MXQ(5) MXQ(6) MXQ(7) MXQ(8) \
            MXQ(9) MXQ(10) MXQ(11) MXQ(12) MXQ(13) MXQ(14) MXQ(15) \
            MXQ(16) MXQ(17) MXQ(18) MXQ(19) MXQ(20) MXQ(21) MXQ(22) \
            MXQ(23) MXQ(24) MXQ(25) MXQ(26) MXQ(27) MXQ(28) MXQ(29) \
            MXQ(30) MXQ(31) MXQ(32) MXQ(33) MXQ(34) MXQ(35) MXQ(36) \
            MXQ(37) MXQ(38) MXQ(39) MXQ(40) MXQ(41) MXQ(42) MXQ(43) \
            MXQ(44) \
            const int ex = (int)(mx >> 23) - 127; \
            q = ldexpf(q, -ex); \
            esum += ex; \
        } \
    }

    // Overflow safety: renormed base <= 2 and per-step growth factor
    // el*rowsum(E) < 2^19 for this data -> 4-step chunk < 2^78 << 2^127.
#pragma unroll 2
    for (int t0 = 0; t0 < len; t0 += 4) {
        const float n0 = LD(t0 + 8), n1 = LD(t0 + 9);
        const float n2 = LD(t0 + 10), n3 = LD(t0 + 11);

        STEP(0, 0) STEP(1, 0) STEP(2, 0) STEP(3, 1)

        f0 = p0; f1 = p1; f2 = p2; f3 = p3;
        p0 = n0; p1 = n1; p2 = n2; p3 = n3;
    }
#undef STEP
#undef MXQ
#undef MAC
#undef INI
#undef RDL
#undef LD

    // --- epilogue: norm = esum*ln2 + LSE_i(log(q_i) + trans[STOP][i]) ---
    const float a = __logf(q) + tstop;       // q=0 (pads) -> -inf
    const float mm = wave_max64(a);
    const float e = __expf(a - mm);          // exp(-inf - mm) = 0
    const float ssum = wave_sum64(e);
    if (lane == 0) {
        const float M = (float)esum * 0.69314718055994531f;
        out[b] = M + mm + __logf(ssum);
    }
}

extern "C" void kernel_launch(void* const* d_in, const int* in_sizes, int n_in,
                              void* d_out, int out_size, void* d_ws, size_t ws_size,
                              hipStream_t stream) {
    const float* logits = (const float*)d_in[0];
    const int* lens = (const int*)d_in[1];
    const float* trans = (const float*)d_in[2];
    float* out = (float*)d_out;

    const int B = in_sizes[1];                       // 1024
    const int S = in_sizes[0] / (B * NL);            // 512

    crf_fwd_kernel<<<B, 64, 0, stream>>>(logits, lens, trans, out, S);
}